// Round 11
// baseline (1619.615 us; speedup 1.0000x reference)
//
#include <hip/hip_runtime.h>
#include <hip/hip_bf16.h>

// B=256, L=2048, H=128, V=32000, THR=0.4, LN_EPS=1e-5. All fp32.
// Htab2 row (RS=136 floats): [0:64)=h[0..63], [64:68)=pad, [68:132)=h[64..127],
// [132]=kk, [133]=inv.
// Scan v8: 2-token super-step on the v7b chassis (R=4/C=8 layout).
// Per super-step (tokens t,t+1), ONE barrier:
//  PRE : u=M k_t, w=M k_{t+1} (row-trees); e=k_t-inv_t u; a=k_{t+1}-inv_{t+1} w;
//        reduce {SE=||e||^2, SC=k_t.k_{t+1}, SAE=a.e, SA=||a||^2} via bcast trees.
//  POST: g_t=SE>0.16kk_t; phi=g_t inv_{t+1} SC; e'=a-phi e;
//        ||e'||^2 = SA-2phi SAE+phi^2 SE -> g_{t+1};  M += g_t e k_t^T + g_{t+1} e' k_{t+1}^T.
// Exact sequential semantics (rank-1 expansion), fp reassociation only.
// 8-slot ring: super issues DMA k_{t+4},k_{t+5}; post-barrier vmcnt(2) retires
// exactly k_{t+2},k_{t+3} which are refilled into the idle pair. 2047 tokens =
// 1023 supers (1020 in 255x4-unrolled loop + 3 tail) + single-step(2046) + r.

#define BB 256
#define LL 2048
#define HH 128
#define VV 32000
#define RS 136

typedef float f32x2 __attribute__((ext_vector_type(2)));

__device__ __forceinline__ void dma16(const float* g, float* l) {
  __builtin_amdgcn_global_load_lds(
      (const __attribute__((address_space(1))) void*)g,
      (__attribute__((address_space(3))) void*)l,
      16, 0, 0);
}

template <int CTRL>
__device__ __forceinline__ float dppadd(float x) {
  int y = __builtin_amdgcn_update_dpp(0, __float_as_int(x), CTRL, 0xF, 0xF, true);
  return x + __int_as_float(y);
}

// d = a*b + d  (packed 2x fp32)
__device__ __forceinline__ void pkfma(f32x2& d, f32x2 a, f32x2 b) {
  asm("v_pk_fma_f32 %0, %1, %2, %0" : "+v"(d) : "v"(a), "v"(b));
}

__device__ __forceinline__ void barrier_lgkm() {
  asm volatile("s_waitcnt lgkmcnt(0)\n\ts_barrier" ::: "memory");
}
__device__ __forceinline__ void wait_vmN(int n) {
  if (n == 2)      asm volatile("s_waitcnt vmcnt(2)" ::: "memory");
  else if (n == 1) asm volatile("s_waitcnt vmcnt(1)" ::: "memory");
  else             asm volatile("s_waitcnt vmcnt(0)" ::: "memory");
}

// ---------------------------------------------------------------------------
// Kernel A: Htab2 row = LN(e + relu(e@W1+b1)@W2 + b2) (+ kk, inv), padded.
// (unchanged from verified baseline)
// ---------------------------------------------------------------------------
__global__ __launch_bounds__(256, 1) void build_htab_kernel(
    const float* __restrict__ embed,
    const float* __restrict__ W1,
    const float* __restrict__ b1,
    const float* __restrict__ W2,
    const float* __restrict__ b2,
    const float* __restrict__ gamma,
    const float* __restrict__ beta,
    float* __restrict__ Htab2)
{
  const int tid = threadIdx.x;
  const int j   = tid & 127;
  const int h2  = tid >> 7;

  float w1r[128];
#pragma unroll
  for (int m = 0; m < 128; ++m) w1r[m] = W1[m * 256 + tid];

  const float b1n = b1[tid];
  const float b2j = b2[j];
  const float gj  = gamma[j];
  const float bj  = beta[j];

  __shared__ __align__(16) float4 w2q[64][128];   // 128 KiB
  __shared__ __align__(16) float e_s[128];
  __shared__ __align__(16) float a_s[256];
  __shared__ float p_s[2][128];
  __shared__ float red[8];

  for (int idx = tid; idx < 8192; idx += 256) {
    int n4 = idx >> 7, jj = idx & 127;
    float4 w;
    w.x = W2[(size_t)(4 * n4 + 0) * 128 + jj];
    w.y = W2[(size_t)(4 * n4 + 1) * 128 + jj];
    w.z = W2[(size_t)(4 * n4 + 2) * 128 + jj];
    w.w = W2[(size_t)(4 * n4 + 3) * 128 + jj];
    w2q[n4][jj] = w;
  }
  __syncthreads();

  for (int v = blockIdx.x; v < VV; v += gridDim.x) {
    if (tid < 128) e_s[tid] = embed[(size_t)v * 128 + tid];
    __syncthreads();

    float acc[4] = {b1n, 0.f, 0.f, 0.f};
#pragma unroll
    for (int q = 0; q < 32; ++q) {
      float4 ev = *(const float4*)&e_s[4 * q];
      float t = ev.x * w1r[4 * q + 0];
      t = fmaf(ev.y, w1r[4 * q + 1], t);
      t = fmaf(ev.z, w1r[4 * q + 2], t);
      t = fmaf(ev.w, w1r[4 * q + 3], t);
      acc[q & 3] += t;
    }
    float a = fmaxf((acc[0] + acc[1]) + (acc[2] + acc[3]), 0.0f);
    a_s[tid] = a;
    __syncthreads();

    float p0 = 0.f, p1 = 0.f, p2v = 0.f, p3 = 0.f;
#pragma unroll
    for (int q = 0; q < 32; ++q) {
      int n4 = h2 * 32 + q;
      float4 av = *(const float4*)&a_s[4 * n4];
      float4 wq = w2q[n4][j];
      p0 = fmaf(av.x, wq.x, p0);
      p1 = fmaf(av.y, wq.y, p1);
      p2v = fmaf(av.z, wq.z, p2v);
      p3 = fmaf(av.w, wq.w, p3);
    }
    p_s[h2][j] = (p0 + p1) + (p2v + p3);
    __syncthreads();

    float y = 0.0f;
    if (tid < 128) {
      float ff = p_s[0][tid] + p_s[1][tid] + b2j;
      y = e_s[tid] + ff;
    }
    float s1 = y, s2 = y * y;
    s1 = dppadd<0xB1>(s1);  s2 = dppadd<0xB1>(s2);
    s1 = dppadd<0x4E>(s1);  s2 = dppadd<0x4E>(s2);
    s1 = dppadd<0x141>(s1); s2 = dppadd<0x141>(s2);
    s1 = dppadd<0x140>(s1); s2 = dppadd<0x140>(s2);
    s1 = dppadd<0x142>(s1); s2 = dppadd<0x142>(s2);
    s1 = dppadd<0x143>(s1); s2 = dppadd<0x143>(s2);
    if (tid < 128 && (tid & 63) == 63) {
      red[tid >> 6] = s1;
      red[2 + (tid >> 6)] = s2;
    }
    __syncthreads();
    float mu = (red[0] + red[1]) * (1.0f / 128.0f);
    float ms = (red[2] + red[3]) * (1.0f / 128.0f);
    float var = ms - mu * mu;
    float hv = 0.0f;
    if (tid < 128) {
      float dy = y - mu;
      hv = dy * (1.0f / sqrtf(var + 1e-5f)) * gj + bj;
      int ofs = tid + ((tid >> 6) << 2);           // padded layout
      Htab2[(size_t)v * RS + ofs] = hv;
    }
    float q2 = hv * hv;
    q2 = dppadd<0xB1>(q2);
    q2 = dppadd<0x4E>(q2);
    q2 = dppadd<0x141>(q2);
    q2 = dppadd<0x140>(q2);
    q2 = dppadd<0x142>(q2);
    q2 = dppadd<0x143>(q2);
    if (tid < 128 && (tid & 63) == 63) red[4 + (tid >> 6)] = q2;
    __syncthreads();
    if (tid == 0) {
      float kk = red[4] + red[5];
      Htab2[(size_t)v * RS + 132] = kk;
      Htab2[(size_t)v * RS + 133] = 1.0f / (kk + 1e-6f);
    }
    __syncthreads();
  }
}

// ---------------------------------------------------------------------------
// Kernel B: per-batch scan, 2-token super-steps. 256 blocks x 512 threads.
// Thread (wv=tid>>6, rg=lane>>4, cg=lane&15) owns rows i0..i0+3 x 8 cols.
// ---------------------------------------------------------------------------
__global__ __launch_bounds__(512, 1) void scan_kernel(
    const int* __restrict__ seq,
    const float* __restrict__ Htab2,
    const float* __restrict__ Wrp,
    const float* __restrict__ brp,
    float* __restrict__ rr)
{
  const int b     = blockIdx.x;
  const int tid   = threadIdx.x;
  const int lane  = tid & 63;
  const int wv    = tid >> 6;               // wave 0..7
  const int rg    = lane >> 4;              // row-group within wave (0..3)
  const int cg    = lane & 15;              // col-group (0..15)
  const int i0    = wv * 16 + rg * 4;       // first owned row
  const int iofs  = i0 + ((i0 >> 6) << 2);  // padded float-offset of rows i0..i0+3
  const int kbase = (cg & 7) * 8 + (cg >> 3) * 68;  // own 8 cols float-offset

  __shared__ int seq_s[LL];
  __shared__ __align__(16) float slots[8][RS];
  __shared__ __align__(16) float4 red4[3][8];   // {SE,SC,SAE,SA} per wave
  __shared__ __align__(16) float red1[8];
  __shared__ __align__(16) float r_s[128];
  __shared__ float p2_s[4][128];

  // token register state: named members only (no arrays -> asm-safe)
  struct KTok {
    f32x2 c0, c1, c2, c3;     // own 8 cols
    float ki0, ki1, ki2, ki3; // own 4 rows
    float kk, inv;
  };

  // prologue DMAs: k0..k3 -> slots 0..3 (every wave issues its own copy)
  {
    int t0 = seq[(size_t)b * LL + 0];
    int t1 = seq[(size_t)b * LL + 1];
    int t2 = seq[(size_t)b * LL + 2];
    int t3 = seq[(size_t)b * LL + 3];
    if (lane < 34) {
      dma16(Htab2 + (size_t)t0 * RS + lane * 4, &slots[0][0]);
      dma16(Htab2 + (size_t)t1 * RS + lane * 4, &slots[1][0]);
      dma16(Htab2 + (size_t)t2 * RS + lane * 4, &slots[2][0]);
      dma16(Htab2 + (size_t)t3 * RS + lane * 4, &slots[3][0]);
    }
  }
  for (int t = tid; t < LL; t += 512) seq_s[t] = seq[(size_t)b * LL + t];
  __syncthreads();   // full drain (incl. prologue DMAs) — once, at start

  // M[row r][col pair m] as 16 NAMED f32x2
  f32x2 M00{0.f,0.f}, M01{0.f,0.f}, M02{0.f,0.f}, M03{0.f,0.f};
  f32x2 M10{0.f,0.f}, M11{0.f,0.f}, M12{0.f,0.f}, M13{0.f,0.f};
  f32x2 M20{0.f,0.f}, M21{0.f,0.f}, M22{0.f,0.f}, M23{0.f,0.f};
  f32x2 M30{0.f,0.f}, M31{0.f,0.f}, M32{0.f,0.f}, M33{0.f,0.f};

  auto loadTok = [&](KTok& T, const float* sp) {
    const f32x2* kp = (const f32x2*)(sp + kbase);
    T.c0 = kp[0]; T.c1 = kp[1]; T.c2 = kp[2]; T.c3 = kp[3];
    float4 k4 = *(const float4*)(sp + iofs);
    T.ki0 = k4.x; T.ki1 = k4.y; T.ki2 = k4.z; T.ki3 = k4.w;
    float2 kv = *(const float2*)(sp + 132);
    T.kk = kv.x; T.inv = kv.y;
  };
  auto pinTok = [&](KTok& T) {
    asm volatile("" : "+v"(T.c0), "+v"(T.c1), "+v"(T.c2), "+v"(T.c3));
    asm volatile("" : "+v"(T.ki0), "+v"(T.ki1), "+v"(T.ki2), "+v"(T.ki3));
    asm volatile("" : "+v"(T.kk), "+v"(T.inv));
  };
  // full row dot of M rows with K's cols; result replicated in all 16 cg lanes
  auto rowdot = [&](const KTok& K, float& v0, float& v1, float& v2, float& v3) {
    f32x2 a0{0.f,0.f}, a1{0.f,0.f}, a2{0.f,0.f}, a3{0.f,0.f};
    pkfma(a0, K.c0, M00); pkfma(a0, K.c1, M01); pkfma(a0, K.c2, M02); pkfma(a0, K.c3, M03);
    pkfma(a1, K.c0, M10); pkfma(a1, K.c1, M11); pkfma(a1, K.c2, M12); pkfma(a1, K.c3, M13);
    pkfma(a2, K.c0, M20); pkfma(a2, K.c1, M21); pkfma(a2, K.c2, M22); pkfma(a2, K.c3, M23);
    pkfma(a3, K.c0, M30); pkfma(a3, K.c1, M31); pkfma(a3, K.c2, M32); pkfma(a3, K.c3, M33);
    v0 = a0.x + a0.y; v1 = a1.x + a1.y; v2 = a2.x + a2.y; v3 = a3.x + a3.y;
    v0 = dppadd<0xB1>(v0);  v1 = dppadd<0xB1>(v1);
    v2 = dppadd<0xB1>(v2);  v3 = dppadd<0xB1>(v3);
    v0 = dppadd<0x4E>(v0);  v1 = dppadd<0x4E>(v1);
    v2 = dppadd<0x4E>(v2);  v3 = dppadd<0x4E>(v3);
    v0 = dppadd<0x141>(v0); v1 = dppadd<0x141>(v1);
    v2 = dppadd<0x141>(v2); v3 = dppadd<0x141>(v3);
    v0 = dppadd<0x140>(v0); v1 = dppadd<0x140>(v1);
    v2 = dppadd<0x140>(v2); v3 = dppadd<0x140>(v3);
  };

  KTok P0{}, P1{}, Q0{}, Q1{};
  loadTok(P0, &slots[0][0]);   // k0
  loadTok(P1, &slots[1][0]);   // k1
  pinTok(P0); pinTok(P1);

  int p = 0;  // red phase (runtime, mod 3)

  // super-step for tokens (t, t+1): C=current pair, R=refill pair (<- k_{t+2},k_{t+3})
  auto superstep = [&](KTok& C0, KTok& C1, KTok& R0, KTok& R1,
                       int t, int sr0, int sr1, int sd0, int sd1,
                       int nwait, int doIssue) {
    // ---- PRE ----
    if (doIssue) {
      int tk0 = seq_s[t + 4];
      int tk1 = seq_s[t + 5];
      if (lane < 34) {
        dma16(Htab2 + (size_t)tk0 * RS + lane * 4, &slots[sd0][0]);
        dma16(Htab2 + (size_t)tk1 * RS + lane * 4, &slots[sd1][0]);
      }
    }
    float u0, u1, u2, u3, w0, w1, w2, w3;
    rowdot(C0, u0, u1, u2, u3);          // u = M k_t
    rowdot(C1, w0, w1, w2, w3);          // w = M k_{t+1}  (M = M_{t-1})
    float e0 = fmaf(-C0.inv, u0, C0.ki0);
    float e1 = fmaf(-C0.inv, u1, C0.ki1);
    float e2 = fmaf(-C0.inv, u2, C0.ki2);
    float e3 = fmaf(-C0.inv, u3, C0.ki3);
    float aa0 = fmaf(-C1.inv, w0, C1.ki0);
    float aa1 = fmaf(-C1.inv, w1, C1.ki1);
    float aa2 = fmaf(-C1.inv, w2, C1.ki2);
    float aa3 = fmaf(-C1.inv, w3, C1.ki3);
    // local partials (cg-uniform), then 2-level bcast tree -> totals in lanes 48-63
    float sE  = fmaf(e3, e3, fmaf(e2, e2, fmaf(e1, e1, e0 * e0)));
    float sC  = fmaf(C0.ki3, C1.ki3, fmaf(C0.ki2, C1.ki2, fmaf(C0.ki1, C1.ki1, C0.ki0 * C1.ki0)));
    float sAE = fmaf(aa3, e3, fmaf(aa2, e2, fmaf(aa1, e1, aa0 * e0)));
    float sA  = fmaf(aa3, aa3, fmaf(aa2, aa2, fmaf(aa1, aa1, aa0 * aa0)));
    sE = dppadd<0x142>(sE);  sC = dppadd<0x142>(sC);
    sAE = dppadd<0x142>(sAE); sA = dppadd<0x142>(sA);
    sE = dppadd<0x143>(sE);  sC = dppadd<0x143>(sC);
    sAE = dppadd<0x143>(sAE); sA = dppadd<0x143>(sA);
    if (lane == 63) red4[p][wv] = float4{sE, sC, sAE, sA};
    barrier_lgkm();                      // lgkmcnt(0)+s_barrier, NO vmcnt drain
    // ---- POST ----
    const float4* rp = (const float4*)&red4[p][0];  // broadcast reads, issue early
    float4 q0 = rp[0], q1 = rp[1], q2 = rp[2], q3 = rp[3];
    float4 q4 = rp[4], q5 = rp[5], q6 = rp[6], q7 = rp[7];
    wait_vmN(nwait);
    loadTok(R0, &slots[sr0][0]);         // k_{t+2} (consumed next super)
    loadTok(R1, &slots[sr1][0]);         // k_{t+3}
    float SE  = ((q0.x + q1.x) + (q2.x + q3.x)) + ((q4.x + q5.x) + (q6.x + q7.x));
    float SC  = ((q0.y + q1.y) + (q2.y + q3.y)) + ((q4.y + q5.y) + (q6.y + q7.y));
    float SAE = ((q0.z + q1.z) + (q2.z + q3.z)) + ((q4.z + q5.z) + (q6.z + q7.z));
    float SA  = ((q0.w + q1.w) + (q2.w + q3.w)) + ((q4.w + q5.w) + (q6.w + q7.w));
    int gA = SE > 0.16f * C0.kk;                    // gate for token t
    float phi = gA ? (C1.inv * SC) : 0.0f;
    float E1 = fmaf(phi, fmaf(phi, SE, -2.0f * SAE), SA);  // ||e_{t+1}||^2
    int gB = E1 > 0.16f * C1.kk;                    // gate for token t+1
    float f0 = gA ? e0 : 0.0f;
    float f1 = gA ? e1 : 0.0f;
    float f2 = gA ? e2 : 0.0f;
    float f3 = gA ? e3 : 0.0f;
    float h0 = fmaf(-phi, e0, aa0);                 // e_{t+1} rows
    float h1 = fmaf(-phi, e1, aa1);
    float h2 = fmaf(-phi, e2, aa2);
    float h3 = fmaf(-phi, e3, aa3);
    float j0 = gB ? h0 : 0.0f;
    float j1 = gB ? h1 : 0.0f;
    float j2 = gB ? h2 : 0.0f;
    float j3 = gB ? h3 : 0.0f;
    f32x2 F0{f0, f0}, F1{f1, f1}, F2{f2, f2}, F3{f3, f3};
    f32x2 J0{j0, j0}, J1{j1, j1}, J2{j2, j2}, J3{j3, j3};
    pkfma(M00, F0, C0.c0); pkfma(M01, F0, C0.c1); pkfma(M02, F0, C0.c2); pkfma(M03, F0, C0.c3);
    pkfma(M10, F1, C0.c0); pkfma(M11, F1, C0.c1); pkfma(M12, F1, C0.c2); pkfma(M13, F1, C0.c3);
    pkfma(M20, F2, C0.c0); pkfma(M21, F2, C0.c1); pkfma(M22, F2, C0.c2); pkfma(M23, F2, C0.c3);
    pkfma(M30, F3, C0.c0); pkfma(M31, F3, C0.c1); pkfma(M32, F3, C0.c2); pkfma(M33, F3, C0.c3);
    pkfma(M00, J0, C1.c0); pkfma(M01, J0, C1.c1); pkfma(M02, J0, C1.c2); pkfma(M03, J0, C1.c3);
    pkfma(M10, J1, C1.c0); pkfma(M11, J1, C1.c1); pkfma(M12, J1, C1.c2); pkfma(M13, J1, C1.c3);
    pkfma(M20, J2, C1.c0); pkfma(M21, J2, C1.c1); pkfma(M22, J2, C1.c2); pkfma(M23, J2, C1.c3);
    pkfma(M30, J3, C1.c0); pkfma(M31, J3, C1.c1); pkfma(M32, J3, C1.c2); pkfma(M33, J3, C1.c3);
    // pin refilled regs AFTER the update so loads hide under red-read + update
    pinTok(R0); pinTok(R1);
    p = (p == 2) ? 0 : (p + 1);
  };

  // main loop: 255 iters x 4 supers = 1020 supers = tokens 0..2039.
  // slot pattern (t mod 8): refill (t+2)&7,(t+3)&7; DMA (t+4)&7,(t+5)&7.
  for (int it = 0; it < 255; ++it) {
    int T = it * 8;
    superstep(P0, P1, Q0, Q1, T + 0, 2, 3, 4, 5, 2, 1);
    superstep(Q0, Q1, P0, P1, T + 2, 4, 5, 6, 7, 2, 1);
    superstep(P0, P1, Q0, Q1, T + 4, 6, 7, 0, 1, 2, 1);
    superstep(Q0, Q1, P0, P1, T + 6, 0, 1, 2, 3, 2, 1);
  }
  // tail supers: tokens 2040..2045 (2040 mod 8 == 0, pattern continues)
  superstep(P0, P1, Q0, Q1, 2040, 2, 3, 4, 5, 2, 1);  // DMA k2044,k2045
  superstep(Q0, Q1, P0, P1, 2042, 4, 5, 6, 7, 2, 1);  // DMA k2046,k2047
  superstep(P0, P1, Q0, Q1, 2044, 6, 7, 0, 1, 0, 0);  // no DMA; refill Q<-k2046,k2047

  // single step: token 2046 (M = M_2045; Q0 = k_2046, Q1 = k_2047)
  {
    float u0, u1, u2, u3;
    rowdot(Q0, u0, u1, u2, u3);
    float e0 = fmaf(-Q0.inv, u0, Q0.ki0);
    float e1 = fmaf(-Q0.inv, u1, Q0.ki1);
    float e2 = fmaf(-Q0.inv, u2, Q0.ki2);
    float e3 = fmaf(-Q0.inv, u3, Q0.ki3);
    float s = fmaf(e3, e3, fmaf(e2, e2, fmaf(e1, e1, e0 * e0)));
    s = dppadd<0x142>(s);
    s = dppadd<0x143>(s);
    if (lane == 63) red1[wv] = s;
    barrier_lgkm();
    float4 ra = *(const float4*)&red1[0];
    float4 rb = *(const float4*)&red1[4];
    float SE = ((ra.x + ra.y) + (ra.z + ra.w)) + ((rb.x + rb.y) + (rb.z + rb.w));
    int g = SE > 0.16f * Q0.kk;
    float f0 = g ? e0 : 0.0f;
    float f1 = g ? e1 : 0.0f;
    float f2 = g ? e2 : 0.0f;
    float f3 = g ? e3 : 0.0f;
    f32x2 F0{f0, f0}, F1{f1, f1}, F2{f2, f2}, F3{f3, f3};
    pkfma(M00, F0, Q0.c0); pkfma(M01, F0, Q0.c1); pkfma(M02, F0, Q0.c2); pkfma(M03, F0, Q0.c3);
    pkfma(M10, F1, Q0.c0); pkfma(M11, F1, Q0.c1); pkfma(M12, F1, Q0.c2); pkfma(M13, F1, Q0.c3);
    pkfma(M20, F2, Q0.c0); pkfma(M21, F2, Q0.c1); pkfma(M22, F2, Q0.c2); pkfma(M23, F2, Q0.c3);
    pkfma(M30, F3, Q0.c0); pkfma(M31, F3, Q0.c1); pkfma(M32, F3, Q0.c2); pkfma(M33, F3, Q0.c3);
    // r = M_2046 @ k_2047
    float v0, v1, v2, v3;
    rowdot(Q1, v0, v1, v2, v3);
    if (cg == 0) {
      *(float4*)&r_s[i0] = float4{v0, v1, v2, v3};
    }
  }
  __syncthreads();

  // rr[b,:] = r @ Wrp + brp  (512 threads: 4 row-groups of 32)
  const int j = tid & 127;
  const int g = tid >> 7;
  float pac[2] = {0.f, 0.f};
#pragma unroll
  for (int m = 0; m < 32; ++m) {
    pac[m & 1] = fmaf(r_s[g * 32 + m],
                      Wrp[(size_t)(g * 32 + m) * 128 + j], pac[m & 1]);
  }
  p2_s[g][j] = pac[0] + pac[1];
  __syncthreads();
  if (tid < 128) {
    rr[(size_t)b * 128 + tid] =
        p2_s[0][tid] + p2_s[1][tid] + p2_s[2][tid] + p2_s[3][tid] + brp[tid];
  }
}

// ---------------------------------------------------------------------------
// Kernel C: out[b,v] = rr[b,:] @ Wout[:,v] + bout[v]  (unchanged)
// ---------------------------------------------------------------------------
__global__ __launch_bounds__(256, 1) void out_kernel(
    const float* __restrict__ rr,
    const float* __restrict__ Wout,
    const float* __restrict__ bout,
    float* __restrict__ out)
{
  const int tid = threadIdx.x;
  const int v = blockIdx.x * 64 + (tid & 63);
  const int bg = tid >> 6;
  const int b0 = blockIdx.y * 64;

  __shared__ float4 rs4[64][32];
  for (int idx = tid; idx < 2048; idx += 256) {
    int bb = idx >> 5, q = idx & 31;
    rs4[bb][q] = ((const float4*)rr)[(size_t)(b0 + bb) * 32 + q];
  }
  __syncthreads();

  float acc[16];
#pragma unroll
  for (int m = 0; m < 16; ++m) acc[m] = 0.0f;

  for (int h4 = 0; h4 < 32; ++h4) {
    float w0 = Wout[(size_t)(4 * h4 + 0) * VV + v];
    float w1 = Wout[(size_t)(4 * h4 + 1) * VV + v];
    float w2 = Wout[(size_t)(4 * h4 + 2) * VV + v];
    float w3 = Wout[(size_t)(4 * h4 + 3) * VV + v];
#pragma unroll
    for (int m = 0; m < 16; ++m) {
      float4 rv = rs4[bg * 16 + m][h4];
      float t = rv.x * w0;
      t = fmaf(rv.y, w1, t);
      t = fmaf(rv.z, w2, t);
      t = fmaf(rv.w, w3, t);
      acc[m] += t;
    }
  }
  float bo = bout[v];
#pragma unroll
  for (int m = 0; m < 16; ++m) {
    out[(size_t)(b0 + bg * 16 + m) * VV + v] = acc[m] + bo;
  }
}

// ---------------------------------------------------------------------------
extern "C" void kernel_launch(void* const* d_in, const int* in_sizes, int n_in,
                              void* d_out, int out_size, void* d_ws, size_t ws_size,
                              hipStream_t stream)
{
  const int* seq      = (const int*)d_in[0];
  const float* embed  = (const float*)d_in[1];
  const float* W1     = (const float*)d_in[2];
  const float* b1     = (const float*)d_in[3];
  const float* W2     = (const float*)d_in[4];
  const float* b2     = (const float*)d_in[5];
  const float* gamma  = (const float*)d_in[6];
  const float* beta   = (const float*)d_in[7];
  const float* Wrp    = (const float*)d_in[8];
  const float* brp    = (const float*)d_in[9];
  const float* Wout   = (const float*)d_in[10];
  const float* bout   = (const float*)d_in[11];
  float* out          = (float*)d_out;

  char* ws = (char*)d_ws;
  float* Htab2 = (float*)ws;                         // 32000*136*4 = 17,408,000 B
  float* rr    = (float*)(ws + 17408000);            //    131,072 B

  hipLaunchKernelGGL(build_htab_kernel, dim3(256), dim3(256), 0, stream,
                     embed, W1, b1, W2, b2, gamma, beta, Htab2);
  hipLaunchKernelGGL(scan_kernel, dim3(BB), dim3(512), 0, stream,
                     seq, Htab2, Wrp, brp, rr);
  hipLaunchKernelGGL(out_kernel, dim3(VV / 64, 4), dim3(256), 0, stream,
                     rr, Wout, bout, out);
}